// Round 6
// baseline (458.110 us; speedup 1.0000x reference)
//
#include <hip/hip_runtime.h>
#include <hip/hip_bf16.h>

#define NEG_SLOPE 0.01f
#define C 128
#define NGRAPH 64

typedef short short8 __attribute__((ext_vector_type(8)));
typedef float f32x4 __attribute__((ext_vector_type(4)));

// monotone float <-> uint mapping for atomicMax-based segment max
__device__ __forceinline__ unsigned fmap(float x){
  unsigned b = __float_as_uint(x);
  return (b & 0x80000000u) ? ~b : (b | 0x80000000u);
}
__device__ __forceinline__ float funmap(unsigned k){
  return (k & 0x80000000u) ? __uint_as_float(k & 0x7FFFFFFFu) : __uint_as_float(~k);
}

// round-to-nearest-even bf16
__device__ __forceinline__ unsigned short bf16_rne(float a){
  unsigned u = __float_as_uint(a);
  return (unsigned short)((u + 0x7FFFu + ((u >> 16) & 1u)) >> 16);
}
// split fp32 into bf16 hi (RNE) + bf16 lo (residual), pack as uint = hi | lo<<16
__device__ __forceinline__ unsigned packsplit(float a){
  unsigned short hi = bf16_rne(a);
  float r = a - __uint_as_float(((unsigned)hi) << 16);
  unsigned short lo = bf16_rne(r);
  return (unsigned)hi | (((unsigned)lo) << 16);
}
// hi part of packed elem as f32:  bf16(lo16bits)
__device__ __forceinline__ float packed_hi_f32(unsigned u){ return __uint_as_float(u << 16); }
// lo part of packed elem as f32:  bf16(hi16bits)
__device__ __forceinline__ float packed_lo_f32(unsigned u){ return __uint_as_float(u & 0xFFFF0000u); }

// ---------- one-time fp32 -> packed hi/lo interleaved ----------
__global__ void split_int(const float* __restrict__ in, unsigned* __restrict__ outp, int n){
  int i = (blockIdx.x * blockDim.x + threadIdx.x) * 2;
  if(i >= n) return;
  float2 v = *(const float2*)(in + i);
  *(uint2*)(outp + i) = make_uint2(packsplit(v.x), packsplit(v.y));
}

// ---------- CSR build ----------
__global__ void deg_kernel(const int* __restrict__ dst, int* __restrict__ deg, int E){
  int e = blockIdx.x * blockDim.x + threadIdx.x;
  if(e < E) atomicAdd(&deg[dst[e]], 1);
}

__global__ void scan_block(const int* __restrict__ deg, int* __restrict__ incl,
                           int* __restrict__ bsum, int N){
  __shared__ int sm[1024];
  int t = threadIdx.x;
  int i = blockIdx.x * 1024 + t;
  int v = (i < N) ? deg[i] : 0;
  sm[t] = v;
  __syncthreads();
  for(int off = 1; off < 1024; off <<= 1){
    int a = (t >= off) ? sm[t - off] : 0;
    __syncthreads();
    sm[t] += a;
    __syncthreads();
  }
  if(i < N) incl[i] = sm[t];
  if(t == 1023) bsum[blockIdx.x] = sm[t];
}

__global__ void scan_bsum(const int* __restrict__ bsum, int* __restrict__ boff, int nb){
  __shared__ int sm[64];
  int t = threadIdx.x;
  sm[t] = (t < nb) ? bsum[t] : 0;
  __syncthreads();
  for(int off = 1; off < 64; off <<= 1){
    int a = (t >= off) ? sm[t - off] : 0;
    __syncthreads();
    sm[t] += a;
    __syncthreads();
  }
  if(t < nb) boff[t] = sm[t] - bsum[t];
}

__global__ void finalize_rows(const int* __restrict__ incl, const int* __restrict__ deg,
                              const int* __restrict__ boff, int* __restrict__ rows,
                              float* __restrict__ inv_deg, int N, int E){
  int i = blockIdx.x * blockDim.x + threadIdx.x;
  if(i < N){
    rows[i] = incl[i] - deg[i] + boff[i >> 10];
    inv_deg[i] = 1.0f / fmaxf((float)deg[i], 1.0f);
  }
  if(i == 0) rows[N] = E;
}

__global__ void csr_fill_kernel(const int* __restrict__ src, const int* __restrict__ dst,
                                const int* __restrict__ row_start, int* __restrict__ cursor,
                                int* __restrict__ csr, int E){
  int e = blockIdx.x * blockDim.x + threadIdx.x;
  if(e >= E) return;
  int d = dst[e];
  int p = atomicAdd(&cursor[d], 1);
  csr[row_start[d] + p] = src[e];
}

// ---------- aggregation: one wave/node, gather packed rows, 4 loads in flight ----------
__global__ __launch_bounds__(256) void agg_csr_int(
    const unsigned* __restrict__ xint, const int* __restrict__ csr,
    const int* __restrict__ row_start, const float* __restrict__ inv_deg,
    unsigned* __restrict__ mint, int N)
{
  int node = blockIdx.x * 4 + (threadIdx.x >> 6);
  if(node >= N) return;
  int lane = threadIdx.x & 63;
  int beg = row_start[node], end = row_start[node + 1];
  float a0 = 0.f, a1 = 0.f;
  for(int base = beg; base < end; base += 64){
    int cnt = end - base; if(cnt > 64) cnt = 64;
    int s_l = (base + lane < end) ? csr[base + lane] : 0;
    int j = 0;
    for(; j + 4 <= cnt; j += 4){
      int s0 = __shfl(s_l, j + 0, 64);
      int s1 = __shfl(s_l, j + 1, 64);
      int s2 = __shfl(s_l, j + 2, 64);
      int s3 = __shfl(s_l, j + 3, 64);
      uint2 u0 = *(const uint2*)(xint + (long long)s0 * C + lane * 2);
      uint2 u1 = *(const uint2*)(xint + (long long)s1 * C + lane * 2);
      uint2 u2 = *(const uint2*)(xint + (long long)s2 * C + lane * 2);
      uint2 u3 = *(const uint2*)(xint + (long long)s3 * C + lane * 2);
      a0 += packed_hi_f32(u0.x) + packed_lo_f32(u0.x);
      a1 += packed_hi_f32(u0.y) + packed_lo_f32(u0.y);
      a0 += packed_hi_f32(u1.x) + packed_lo_f32(u1.x);
      a1 += packed_hi_f32(u1.y) + packed_lo_f32(u1.y);
      a0 += packed_hi_f32(u2.x) + packed_lo_f32(u2.x);
      a1 += packed_hi_f32(u2.y) + packed_lo_f32(u2.y);
      a0 += packed_hi_f32(u3.x) + packed_lo_f32(u3.x);
      a1 += packed_hi_f32(u3.y) + packed_lo_f32(u3.y);
    }
    for(; j < cnt; j++){
      int s = __shfl(s_l, j, 64);
      uint2 u = *(const uint2*)(xint + (long long)s * C + lane * 2);
      a0 += packed_hi_f32(u.x) + packed_lo_f32(u.x);
      a1 += packed_hi_f32(u.y) + packed_lo_f32(u.y);
    }
  }
  float sc = inv_deg[node];
  *(uint2*)(mint + (long long)node * C + lane * 2) =
      make_uint2(packsplit(a0 * sc), packsplit(a1 * sc));
}

// ---------- weight pre-pack into MFMA B-fragment layout, bf16 hi/lo planes ----------
// B = [W_l ; W_r] (256 x 128).  frag index: (((kstep*4 + kg)*128 + n)*8 + j)
// where k = kstep*32 + kg*8 + j.  hi at [0 .. 32767], lo at [32768 ..].
__global__ void pack_kernel(const float* __restrict__ Wl, const float* __restrict__ Wr,
                            short* __restrict__ Bpk){
  int idx = blockIdx.x * blockDim.x + threadIdx.x;   // 0 .. 32767
  if(idx >= 2 * C * C) return;
  int k = idx >> 7, n = idx & 127;
  float w = (k < C) ? Wl[k * C + n] : Wr[(k - C) * C + n];
  unsigned u = packsplit(w);
  int kstep = k >> 5, kg = (k >> 3) & 3, j = k & 7;
  int pos = ((kstep * 4 + kg) * C + n) * 8 + j;
  Bpk[pos] = (short)(u & 0xFFFFu);
  Bpk[pos + 32768] = (short)(u >> 16);
}

union S8U { short8 s; unsigned u[4]; };

// de-interleave 8 packed elems (two uint4) into hi/lo short8 via v_perm
__device__ __forceinline__ void deint(const uint4& a0, const uint4& a1, S8U& h, S8U& l){
  h.u[0] = __builtin_amdgcn_perm(a0.y, a0.x, 0x05040100u);
  h.u[1] = __builtin_amdgcn_perm(a0.w, a0.z, 0x05040100u);
  h.u[2] = __builtin_amdgcn_perm(a1.y, a1.x, 0x05040100u);
  h.u[3] = __builtin_amdgcn_perm(a1.w, a1.z, 0x05040100u);
  l.u[0] = __builtin_amdgcn_perm(a0.y, a0.x, 0x07060302u);
  l.u[1] = __builtin_amdgcn_perm(a0.w, a0.z, 0x07060302u);
  l.u[2] = __builtin_amdgcn_perm(a1.y, a1.x, 0x07060302u);
  l.u[3] = __builtin_amdgcn_perm(a1.w, a1.z, 0x07060302u);
}

struct Frags {
  uint4 a[4][2];
  short8 bh[2], bl[2];
};

// ---------- MFMA GEMM: h = leakyrelu([mean | x] @ B + bias) ----------
// 64 rows x 128 cols per block, 4 waves each 64x32 (wn = wave). 782 blocks.
// Register double-buffer prefetch of next k-step fragments.
// 3 MFMA passes: Ahi*Bhi + Alo*Bhi + Ahi*Blo (~fp32 accuracy).
__global__ __launch_bounds__(256) void gemm_mfma3(
    const unsigned* __restrict__ Amean, const unsigned* __restrict__ Ax,
    const short* __restrict__ Bpk, const float* __restrict__ bias,
    unsigned* __restrict__ Hout, int M,
    const int* __restrict__ batch, unsigned* __restrict__ pooled)
{
  int tid = threadIdx.x;
  int bm = blockIdx.x * 64;
  int lane = tid & 63;
  int wn = tid >> 6;         // wave = col strip
  int lg = lane >> 4;        // k-group (A/B), row-group (C/D)
  int lm = lane & 15;        // m (A) / n (B) / col (C/D)

  f32x4 acc[4][2];
#pragma unroll
  for(int i = 0; i < 4; i++)
#pragma unroll
    for(int j = 0; j < 2; j++)
      acc[i][j] = (f32x4){0.f, 0.f, 0.f, 0.f};

  Frags f0, f1;

  auto load_frags = [&](int ks, Frags& f){
    const unsigned* Ap = (ks < 4) ? Amean : Ax;
    int kcol = (ks & 3) * 32 + lg * 8;
#pragma unroll
    for(int i = 0; i < 4; i++){
      int row = bm + i * 16 + lm;
      if(row < M){
        const unsigned* p = Ap + (long long)row * C + kcol;
        f.a[i][0] = *(const uint4*)p;
        f.a[i][1] = *(const uint4*)(p + 4);
      }else{
        f.a[i][0] = make_uint4(0, 0, 0, 0);
        f.a[i][1] = make_uint4(0, 0, 0, 0);
      }
    }
#pragma unroll
    for(int j = 0; j < 2; j++){
      const short* bp = Bpk + (((ks * 4 + lg) * C) + wn * 32 + j * 16 + lm) * 8;
      f.bh[j] = *(const short8*)bp;
      f.bl[j] = *(const short8*)(bp + 32768);
    }
  };

  load_frags(0, f0);
#pragma unroll
  for(int ks = 0; ks < 8; ks++){
    Frags& cur = (ks & 1) ? f1 : f0;
    Frags& nxt = (ks & 1) ? f0 : f1;
    if(ks < 7) load_frags(ks + 1, nxt);
#pragma unroll
    for(int i = 0; i < 4; i++){
      S8U h, l;
      deint(cur.a[i][0], cur.a[i][1], h, l);
#pragma unroll
      for(int j = 0; j < 2; j++){
        acc[i][j] = __builtin_amdgcn_mfma_f32_16x16x32_bf16(h.s, cur.bh[j], acc[i][j], 0, 0, 0);
        acc[i][j] = __builtin_amdgcn_mfma_f32_16x16x32_bf16(l.s, cur.bh[j], acc[i][j], 0, 0, 0);
        acc[i][j] = __builtin_amdgcn_mfma_f32_16x16x32_bf16(h.s, cur.bl[j], acc[i][j], 0, 0, 0);
      }
    }
  }

  // ---- epilogue: C/D layout col=lane&15, row=(lane>>4)*4+reg ----
  if(pooled == nullptr){
#pragma unroll
    for(int j = 0; j < 2; j++){
      int col = wn * 32 + j * 16 + lm;
      float bv = bias[col];
#pragma unroll
      for(int i = 0; i < 4; i++){
#pragma unroll
        for(int reg = 0; reg < 4; reg++){
          int row = bm + i * 16 + lg * 4 + reg;
          if(row < M){
            float v = acc[i][j][reg] + bv;
            v = v > 0.f ? v : NEG_SLOPE * v;
            Hout[(long long)row * C + col] = packsplit(v);
          }
        }
      }
    }
  }else{
    // fused global-max-pool: reg-quad covers 4 consecutive rows
#pragma unroll
    for(int i = 0; i < 4; i++){
      int row0 = bm + i * 16 + lg * 4;
      if(row0 >= M) continue;
      bool whole = (row0 + 3 < M);
      int g0 = batch[row0];
      bool same = whole && (batch[row0 + 3] == g0);
#pragma unroll
      for(int j = 0; j < 2; j++){
        int col = wn * 32 + j * 16 + lm;
        float bv = bias[col];
        float v0 = acc[i][j][0] + bv; v0 = v0 > 0.f ? v0 : NEG_SLOPE * v0;
        float v1 = acc[i][j][1] + bv; v1 = v1 > 0.f ? v1 : NEG_SLOPE * v1;
        float v2 = acc[i][j][2] + bv; v2 = v2 > 0.f ? v2 : NEG_SLOPE * v2;
        float v3 = acc[i][j][3] + bv; v3 = v3 > 0.f ? v3 : NEG_SLOPE * v3;
        if(same){
          float m01 = fmaxf(v0, v1), m23 = fmaxf(v2, v3);
          atomicMax(&pooled[g0 * C + col], fmap(fmaxf(m01, m23)));
        }else{
          float vv[4] = {v0, v1, v2, v3};
#pragma unroll
          for(int reg = 0; reg < 4; reg++){
            int row = row0 + reg;
            if(row < M) atomicMax(&pooled[batch[row] * C + col], fmap(vv[reg]));
          }
        }
      }
    }
  }
}

__global__ void fc_kernel(const unsigned* __restrict__ pooled_u, const float* __restrict__ Wfc,
                          const float* __restrict__ bfc, float* __restrict__ out){
  int t = threadIdx.x;   // 0..127
  int g = t >> 1, o = t & 1;
  float s = bfc[o];
  for(int k = 0; k < C; k++)
    s += funmap(pooled_u[g * C + k]) * Wfc[k * 2 + o];
  out[g * 2 + o] = s;
}

extern "C" void kernel_launch(void* const* d_in, const int* in_sizes, int n_in,
                              void* d_out, int out_size, void* d_ws, size_t ws_size,
                              hipStream_t stream) {
  const float* x    = (const float*)d_in[0];
  const int*   ei   = (const int*)d_in[1];
  const int*   batch= (const int*)d_in[2];
  const float* W1l  = (const float*)d_in[3];
  const float* b1   = (const float*)d_in[4];
  const float* W1r  = (const float*)d_in[5];
  const float* W2l  = (const float*)d_in[6];
  const float* b2   = (const float*)d_in[7];
  const float* W2r  = (const float*)d_in[8];
  const float* W3l  = (const float*)d_in[9];
  const float* b3   = (const float*)d_in[10];
  const float* W3r  = (const float*)d_in[11];
  const float* Wfc  = (const float*)d_in[12];
  const float* bfc  = (const float*)d_in[13];
  float* out = (float*)d_out;

  const int N = in_sizes[0] / C;   // 50000
  const int E = in_sizes[1] / 2;   // 600000
  const int* srcv = ei;
  const int* dstv = ei + E;

  char* ws = (char*)d_ws;
  size_t off = 0;
  auto alloc = [&](size_t bytes) -> void* {
    void* p = ws + off;
    off += (bytes + 255) & ~(size_t)255;
    return p;
  };
  int*      deg    = (int*)alloc((size_t)N * 4);
  float*    inv_d  = (float*)alloc((size_t)N * 4);
  int*      incl   = (int*)alloc((size_t)N * 4);
  int*      bsum   = (int*)alloc((size_t)64 * 4);
  int*      boff   = (int*)alloc((size_t)64 * 4);
  int*      rows   = (int*)alloc((size_t)(N + 1) * 4);
  int*      cursor = (int*)alloc((size_t)N * 4);
  int*      csr    = (int*)alloc((size_t)E * 4);
  // packed hi/lo interleaved activation planes
  unsigned* xint   = (unsigned*)alloc((size_t)N * C * 4);
  unsigned* mint   = (unsigned*)alloc((size_t)N * C * 4);
  unsigned* h1int  = (unsigned*)alloc((size_t)N * C * 4);
  short*    B1     = (short*)alloc((size_t)2 * 2 * C * C * 2);
  short*    B2     = (short*)alloc((size_t)2 * 2 * C * C * 2);
  short*    B3     = (short*)alloc((size_t)2 * 2 * C * C * 2);
  unsigned* pooled = (unsigned*)alloc((size_t)NGRAPH * C * 4);

  hipMemsetAsync(deg, 0, (size_t)N * 4, stream);
  hipMemsetAsync(cursor, 0, (size_t)N * 4, stream);
  hipMemsetAsync(pooled, 0, (size_t)NGRAPH * C * 4, stream);

  const int nb = (N + 1023) / 1024;   // 49
  split_int<<<(N * C / 2 + 255) / 256, 256, 0, stream>>>(x, xint, N * C);
  deg_kernel<<<(E + 255) / 256, 256, 0, stream>>>(dstv, deg, E);
  scan_block<<<nb, 1024, 0, stream>>>(deg, incl, bsum, N);
  scan_bsum<<<1, 64, 0, stream>>>(bsum, boff, nb);
  finalize_rows<<<(N + 255) / 256, 256, 0, stream>>>(incl, deg, boff, rows, inv_d, N, E);
  csr_fill_kernel<<<(E + 255) / 256, 256, 0, stream>>>(srcv, dstv, rows, cursor, csr, E);

  pack_kernel<<<(2 * C * C + 255) / 256, 256, 0, stream>>>(W1l, W1r, B1);
  pack_kernel<<<(2 * C * C + 255) / 256, 256, 0, stream>>>(W2l, W2r, B2);
  pack_kernel<<<(2 * C * C + 255) / 256, 256, 0, stream>>>(W3l, W3r, B3);

  int gemmblocks = (N + 63) / 64;   // 782
  int aggblocks = (N + 3) / 4;      // 4 nodes (waves) per 256-thread block

  // layer 1: x -> h1
  agg_csr_int<<<aggblocks, 256, 0, stream>>>(xint, csr, rows, inv_d, mint, N);
  gemm_mfma3<<<gemmblocks, 256, 0, stream>>>(mint, xint, B1, b1, h1int, N, nullptr, nullptr);
  // layer 2: h1 -> h2 (stored into xint)
  agg_csr_int<<<aggblocks, 256, 0, stream>>>(h1int, csr, rows, inv_d, mint, N);
  gemm_mfma3<<<gemmblocks, 256, 0, stream>>>(mint, h1int, B2, b2, xint, N, nullptr, nullptr);
  // layer 3: h2 -> pooled (fused global-max-pool epilogue)
  agg_csr_int<<<aggblocks, 256, 0, stream>>>(xint, csr, rows, inv_d, mint, N);
  gemm_mfma3<<<gemmblocks, 256, 0, stream>>>(mint, xint, B3, b3, nullptr, N, batch, pooled);

  fc_kernel<<<1, 128, 0, stream>>>(pooled, Wfc, bfc, out);
}

// Round 7
// 351.539 us; speedup vs baseline: 1.3032x; 1.3032x over previous
//
#include <hip/hip_runtime.h>
#include <hip/hip_bf16.h>

#define NEG_SLOPE 0.01f
#define C 128
#define NGRAPH 64

typedef short short8 __attribute__((ext_vector_type(8)));
typedef float f32x4 __attribute__((ext_vector_type(4)));
typedef unsigned short ushort;

// monotone float <-> uint mapping for atomicMax-based segment max
__device__ __forceinline__ unsigned fmap(float x){
  unsigned b = __float_as_uint(x);
  return (b & 0x80000000u) ? ~b : (b | 0x80000000u);
}
__device__ __forceinline__ float funmap(unsigned k){
  return (k & 0x80000000u) ? __uint_as_float(k & 0x7FFFFFFFu) : __uint_as_float(~k);
}

// round-to-nearest-even bf16
__device__ __forceinline__ ushort bf16_rne(float a){
  unsigned u = __float_as_uint(a);
  return (ushort)((u + 0x7FFFu + ((u >> 16) & 1u)) >> 16);
}
__device__ __forceinline__ float b2f(ushort h){
  return __uint_as_float(((unsigned)h) << 16);
}

// ---------- one-time fp32 -> bf16 plane ----------
__global__ void to_bf16(const float* __restrict__ in, ushort* __restrict__ o, int n){
  int i = (blockIdx.x * blockDim.x + threadIdx.x) * 4;
  if(i >= n) return;
  float4 v = *(const float4*)(in + i);
  ushort4 r = make_ushort4(bf16_rne(v.x), bf16_rne(v.y), bf16_rne(v.z), bf16_rne(v.w));
  *(ushort4*)(o + i) = r;
}

// ---------- CSR build ----------
__global__ void deg_kernel(const int* __restrict__ dst, int* __restrict__ deg, int E){
  int e = blockIdx.x * blockDim.x + threadIdx.x;
  if(e < E) atomicAdd(&deg[dst[e]], 1);
}

__global__ void scan_block(const int* __restrict__ deg, int* __restrict__ incl,
                           int* __restrict__ bsum, int N){
  __shared__ int sm[1024];
  int t = threadIdx.x;
  int i = blockIdx.x * 1024 + t;
  int v = (i < N) ? deg[i] : 0;
  sm[t] = v;
  __syncthreads();
  for(int off = 1; off < 1024; off <<= 1){
    int a = (t >= off) ? sm[t - off] : 0;
    __syncthreads();
    sm[t] += a;
    __syncthreads();
  }
  if(i < N) incl[i] = sm[t];
  if(t == 1023) bsum[blockIdx.x] = sm[t];
}

__global__ void scan_bsum(const int* __restrict__ bsum, int* __restrict__ boff, int nb){
  __shared__ int sm[64];
  int t = threadIdx.x;
  sm[t] = (t < nb) ? bsum[t] : 0;
  __syncthreads();
  for(int off = 1; off < 64; off <<= 1){
    int a = (t >= off) ? sm[t - off] : 0;
    __syncthreads();
    sm[t] += a;
    __syncthreads();
  }
  if(t < nb) boff[t] = sm[t] - bsum[t];
}

__global__ void finalize_rows(const int* __restrict__ incl, const int* __restrict__ deg,
                              const int* __restrict__ boff, int* __restrict__ rows,
                              float* __restrict__ inv_deg, int N, int E){
  int i = blockIdx.x * blockDim.x + threadIdx.x;
  if(i < N){
    rows[i] = incl[i] - deg[i] + boff[i >> 10];
    inv_deg[i] = 1.0f / fmaxf((float)deg[i], 1.0f);
  }
  if(i == 0) rows[N] = E;
}

__global__ void csr_fill_kernel(const int* __restrict__ src, const int* __restrict__ dst,
                                const int* __restrict__ row_start, int* __restrict__ cursor,
                                int* __restrict__ csr, int E){
  int e = blockIdx.x * blockDim.x + threadIdx.x;
  if(e >= E) return;
  int d = dst[e];
  int p = atomicAdd(&cursor[d], 1);
  csr[row_start[d] + p] = src[e];
}

// ---------- aggregation: one wave/node, 2 edges per 512-B wave load ----------
// lanes 0-31 cover edge j (256-B bf16 row), lanes 32-63 edge j+1; xor-32 combine.
__global__ __launch_bounds__(256) void agg_csr_bf(
    const ushort* __restrict__ xb, const int* __restrict__ csr,
    const int* __restrict__ row_start, const float* __restrict__ inv_deg,
    ushort* __restrict__ mb, int N)
{
  int node = blockIdx.x * 4 + (threadIdx.x >> 6);
  if(node >= N) return;
  int lane = threadIdx.x & 63;
  int half = lane >> 5;      // which edge of the pair
  int hl = lane & 31;        // covers cols hl*4 .. hl*4+3
  int beg = row_start[node], end = row_start[node + 1];
  float a0 = 0.f, a1 = 0.f, a2 = 0.f, a3 = 0.f;

  for(int base = beg; base < end; base += 64){
    int cnt = end - base; if(cnt > 64) cnt = 64;
    int s_l = (base + lane < end) ? csr[base + lane] : 0;
    int j = 0;
    for(; j + 8 <= cnt; j += 8){
      int s0 = __shfl(s_l, j + 0 + half, 64);
      int s1 = __shfl(s_l, j + 2 + half, 64);
      int s2 = __shfl(s_l, j + 4 + half, 64);
      int s3 = __shfl(s_l, j + 6 + half, 64);
      ushort4 v0 = *(const ushort4*)(xb + (long long)s0 * C + hl * 4);
      ushort4 v1 = *(const ushort4*)(xb + (long long)s1 * C + hl * 4);
      ushort4 v2 = *(const ushort4*)(xb + (long long)s2 * C + hl * 4);
      ushort4 v3 = *(const ushort4*)(xb + (long long)s3 * C + hl * 4);
      a0 += b2f(v0.x); a1 += b2f(v0.y); a2 += b2f(v0.z); a3 += b2f(v0.w);
      a0 += b2f(v1.x); a1 += b2f(v1.y); a2 += b2f(v1.z); a3 += b2f(v1.w);
      a0 += b2f(v2.x); a1 += b2f(v2.y); a2 += b2f(v2.z); a3 += b2f(v2.w);
      a0 += b2f(v3.x); a1 += b2f(v3.y); a2 += b2f(v3.z); a3 += b2f(v3.w);
    }
    for(; j < cnt; j += 2){
      int jj = j + half;
      bool valid = jj < cnt;
      int idx = valid ? jj : (cnt - 1);
      int s = __shfl(s_l, idx, 64);
      ushort4 v = *(const ushort4*)(xb + (long long)s * C + hl * 4);
      if(valid){
        a0 += b2f(v.x); a1 += b2f(v.y); a2 += b2f(v.z); a3 += b2f(v.w);
      }
    }
  }
  // combine the two edge-halves
  a0 += __shfl_xor(a0, 32, 64);
  a1 += __shfl_xor(a1, 32, 64);
  a2 += __shfl_xor(a2, 32, 64);
  a3 += __shfl_xor(a3, 32, 64);
  if(half == 0){
    float sc = inv_deg[node];
    ushort4 o = make_ushort4(bf16_rne(a0 * sc), bf16_rne(a1 * sc),
                             bf16_rne(a2 * sc), bf16_rne(a3 * sc));
    *(ushort4*)(mb + (long long)node * C + hl * 4) = o;
  }
}

// ---------- weight pre-pack into MFMA B-fragment layout, bf16 hi/lo planes ----------
// B = [W_l ; W_r] (256 x 128).  frag index: (((kstep*4 + kg)*128 + n)*8 + j)
// where k = kstep*32 + kg*8 + j.  hi at [0 .. 32767], lo at [32768 ..].
__global__ void pack_kernel(const float* __restrict__ Wl, const float* __restrict__ Wr,
                            short* __restrict__ Bpk){
  int idx = blockIdx.x * blockDim.x + threadIdx.x;   // 0 .. 32767
  if(idx >= 2 * C * C) return;
  int k = idx >> 7, n = idx & 127;
  float w = (k < C) ? Wl[k * C + n] : Wr[(k - C) * C + n];
  ushort hi = bf16_rne(w);
  float r = w - b2f(hi);
  ushort lo = bf16_rne(r);
  int kstep = k >> 5, kg = (k >> 3) & 3, j = k & 7;
  int pos = ((kstep * 4 + kg) * C + n) * 8 + j;
  Bpk[pos] = (short)hi;
  Bpk[pos + 32768] = (short)lo;
}

struct Frags {
  short8 a[4];
  short8 bh[2], bl[2];
};

// ---------- MFMA GEMM: h = leakyrelu([mean | x] @ B + bias) ----------
// A is bf16 plane, fragments loaded directly (A[m=lane&15][k=(lane>>4)*8+j], 16 B/lane).
// 2 MFMA passes: A*Bhi + A*Blo (weights ~exact, activation storage err only).
// 64 rows x 128 cols per block, 4 waves each 64x32 col strip. Register dbuf prefetch.
__global__ __launch_bounds__(256, 4) void gemm_mfma4(
    const ushort* __restrict__ Amean, const ushort* __restrict__ Ax,
    const short* __restrict__ Bpk, const float* __restrict__ bias,
    ushort* __restrict__ Hout, int M,
    const int* __restrict__ batch, unsigned* __restrict__ pooled)
{
  int tid = threadIdx.x;
  int bm = blockIdx.x * 64;
  int lane = tid & 63;
  int wn = tid >> 6;         // wave = col strip
  int lg = lane >> 4;        // k-group (A/B), row-group (C/D)
  int lm = lane & 15;        // m (A) / n (B) / col (C/D)

  f32x4 acc[4][2];
#pragma unroll
  for(int i = 0; i < 4; i++)
#pragma unroll
    for(int j = 0; j < 2; j++)
      acc[i][j] = (f32x4){0.f, 0.f, 0.f, 0.f};

  const short8 zfrag = {0, 0, 0, 0, 0, 0, 0, 0};
  Frags f0, f1;

  auto load_frags = [&](int ks, Frags& f){
    const ushort* Ap = (ks < 4) ? Amean : Ax;
    int kcol = (ks & 3) * 32 + lg * 8;
#pragma unroll
    for(int i = 0; i < 4; i++){
      int row = bm + i * 16 + lm;
      f.a[i] = (row < M) ? *(const short8*)(Ap + (long long)row * C + kcol) : zfrag;
    }
#pragma unroll
    for(int j = 0; j < 2; j++){
      const short* bp = Bpk + (((ks * 4 + lg) * C) + wn * 32 + j * 16 + lm) * 8;
      f.bh[j] = *(const short8*)bp;
      f.bl[j] = *(const short8*)(bp + 32768);
    }
  };

  load_frags(0, f0);
#pragma unroll
  for(int ks = 0; ks < 8; ks++){
    Frags& cur = (ks & 1) ? f1 : f0;
    Frags& nxt = (ks & 1) ? f0 : f1;
    if(ks < 7) load_frags(ks + 1, nxt);
#pragma unroll
    for(int i = 0; i < 4; i++){
#pragma unroll
      for(int j = 0; j < 2; j++){
        acc[i][j] = __builtin_amdgcn_mfma_f32_16x16x32_bf16(cur.a[i], cur.bh[j], acc[i][j], 0, 0, 0);
        acc[i][j] = __builtin_amdgcn_mfma_f32_16x16x32_bf16(cur.a[i], cur.bl[j], acc[i][j], 0, 0, 0);
      }
    }
  }

  // ---- epilogue: C/D layout col=lane&15, row=(lane>>4)*4+reg ----
  if(pooled == nullptr){
#pragma unroll
    for(int j = 0; j < 2; j++){
      int col = wn * 32 + j * 16 + lm;
      float bv = bias[col];
#pragma unroll
      for(int i = 0; i < 4; i++){
#pragma unroll
        for(int reg = 0; reg < 4; reg++){
          int row = bm + i * 16 + lg * 4 + reg;
          if(row < M){
            float v = acc[i][j][reg] + bv;
            v = v > 0.f ? v : NEG_SLOPE * v;
            Hout[(long long)row * C + col] = bf16_rne(v);
          }
        }
      }
    }
  }else{
    // fused global-max-pool: reg-quad covers 4 consecutive rows
#pragma unroll
    for(int i = 0; i < 4; i++){
      int row0 = bm + i * 16 + lg * 4;
      if(row0 >= M) continue;
      bool whole = (row0 + 3 < M);
      int g0 = batch[row0];
      bool same = whole && (batch[row0 + 3] == g0);
#pragma unroll
      for(int j = 0; j < 2; j++){
        int col = wn * 32 + j * 16 + lm;
        float bv = bias[col];
        float v0 = acc[i][j][0] + bv; v0 = v0 > 0.f ? v0 : NEG_SLOPE * v0;
        float v1 = acc[i][j][1] + bv; v1 = v1 > 0.f ? v1 : NEG_SLOPE * v1;
        float v2 = acc[i][j][2] + bv; v2 = v2 > 0.f ? v2 : NEG_SLOPE * v2;
        float v3 = acc[i][j][3] + bv; v3 = v3 > 0.f ? v3 : NEG_SLOPE * v3;
        if(same){
          float m01 = fmaxf(v0, v1), m23 = fmaxf(v2, v3);
          atomicMax(&pooled[g0 * C + col], fmap(fmaxf(m01, m23)));
        }else{
          float vv[4] = {v0, v1, v2, v3};
#pragma unroll
          for(int reg = 0; reg < 4; reg++){
            int row = row0 + reg;
            if(row < M) atomicMax(&pooled[batch[row] * C + col], fmap(vv[reg]));
          }
        }
      }
    }
  }
}

__global__ void fc_kernel(const unsigned* __restrict__ pooled_u, const float* __restrict__ Wfc,
                          const float* __restrict__ bfc, float* __restrict__ out){
  int t = threadIdx.x;   // 0..127
  int g = t >> 1, o = t & 1;
  float s = bfc[o];
  for(int k = 0; k < C; k++)
    s += funmap(pooled_u[g * C + k]) * Wfc[k * 2 + o];
  out[g * 2 + o] = s;
}

extern "C" void kernel_launch(void* const* d_in, const int* in_sizes, int n_in,
                              void* d_out, int out_size, void* d_ws, size_t ws_size,
                              hipStream_t stream) {
  const float* x    = (const float*)d_in[0];
  const int*   ei   = (const int*)d_in[1];
  const int*   batch= (const int*)d_in[2];
  const float* W1l  = (const float*)d_in[3];
  const float* b1   = (const float*)d_in[4];
  const float* W1r  = (const float*)d_in[5];
  const float* W2l  = (const float*)d_in[6];
  const float* b2   = (const float*)d_in[7];
  const float* W2r  = (const float*)d_in[8];
  const float* W3l  = (const float*)d_in[9];
  const float* b3   = (const float*)d_in[10];
  const float* W3r  = (const float*)d_in[11];
  const float* Wfc  = (const float*)d_in[12];
  const float* bfc  = (const float*)d_in[13];
  float* out = (float*)d_out;

  const int N = in_sizes[0] / C;   // 50000
  const int E = in_sizes[1] / 2;   // 600000
  const int* srcv = ei;
  const int* dstv = ei + E;

  char* ws = (char*)d_ws;
  size_t off = 0;
  auto alloc = [&](size_t bytes) -> void* {
    void* p = ws + off;
    off += (bytes + 255) & ~(size_t)255;
    return p;
  };
  int*      deg    = (int*)alloc((size_t)N * 4);
  float*    inv_d  = (float*)alloc((size_t)N * 4);
  int*      incl   = (int*)alloc((size_t)N * 4);
  int*      bsum   = (int*)alloc((size_t)64 * 4);
  int*      boff   = (int*)alloc((size_t)64 * 4);
  int*      rows   = (int*)alloc((size_t)(N + 1) * 4);
  int*      cursor = (int*)alloc((size_t)N * 4);
  int*      csr    = (int*)alloc((size_t)E * 4);
  // bf16 activation planes
  ushort*   xb     = (ushort*)alloc((size_t)N * C * 2);
  ushort*   mb     = (ushort*)alloc((size_t)N * C * 2);
  ushort*   h1b    = (ushort*)alloc((size_t)N * C * 2);
  short*    B1     = (short*)alloc((size_t)2 * 2 * C * C * 2);
  short*    B2     = (short*)alloc((size_t)2 * 2 * C * C * 2);
  short*    B3     = (short*)alloc((size_t)2 * 2 * C * C * 2);
  unsigned* pooled = (unsigned*)alloc((size_t)NGRAPH * C * 4);

  hipMemsetAsync(deg, 0, (size_t)N * 4, stream);
  hipMemsetAsync(cursor, 0, (size_t)N * 4, stream);
  hipMemsetAsync(pooled, 0, (size_t)NGRAPH * C * 4, stream);

  const int nb = (N + 1023) / 1024;   // 49
  to_bf16<<<(N * C / 4 + 255) / 256, 256, 0, stream>>>(x, xb, N * C);
  deg_kernel<<<(E + 255) / 256, 256, 0, stream>>>(dstv, deg, E);
  scan_block<<<nb, 1024, 0, stream>>>(deg, incl, bsum, N);
  scan_bsum<<<1, 64, 0, stream>>>(bsum, boff, nb);
  finalize_rows<<<(N + 255) / 256, 256, 0, stream>>>(incl, deg, boff, rows, inv_d, N, E);
  csr_fill_kernel<<<(E + 255) / 256, 256, 0, stream>>>(srcv, dstv, rows, cursor, csr, E);

  pack_kernel<<<(2 * C * C + 255) / 256, 256, 0, stream>>>(W1l, W1r, B1);
  pack_kernel<<<(2 * C * C + 255) / 256, 256, 0, stream>>>(W2l, W2r, B2);
  pack_kernel<<<(2 * C * C + 255) / 256, 256, 0, stream>>>(W3l, W3r, B3);

  int gemmblocks = (N + 63) / 64;   // 782
  int aggblocks = (N + 3) / 4;      // 1 node per wave

  // layer 1: x -> h1
  agg_csr_bf<<<aggblocks, 256, 0, stream>>>(xb, csr, rows, inv_d, mb, N);
  gemm_mfma4<<<gemmblocks, 256, 0, stream>>>(mb, xb, B1, b1, h1b, N, nullptr, nullptr);
  // layer 2: h1 -> h2 (stored into xb)
  agg_csr_bf<<<aggblocks, 256, 0, stream>>>(h1b, csr, rows, inv_d, mb, N);
  gemm_mfma4<<<gemmblocks, 256, 0, stream>>>(mb, h1b, B2, b2, xb, N, nullptr, nullptr);
  // layer 3: h2 -> pooled (fused global-max-pool epilogue)
  agg_csr_bf<<<aggblocks, 256, 0, stream>>>(xb, csr, rows, inv_d, mb, N);
  gemm_mfma4<<<gemmblocks, 256, 0, stream>>>(mb, xb, B3, b3, nullptr, N, batch, pooled);

  fc_kernel<<<1, 128, 0, stream>>>(pooled, Wfc, bfc, out);
}

// Round 8
// 312.435 us; speedup vs baseline: 1.4663x; 1.1252x over previous
//
#include <hip/hip_runtime.h>
#include <hip/hip_bf16.h>

#define NEG_SLOPE 0.01f
#define C 128
#define NGRAPH 64

typedef short short8 __attribute__((ext_vector_type(8)));
typedef float f32x4 __attribute__((ext_vector_type(4)));
typedef unsigned short ushort;

// monotone float <-> uint mapping for atomicMax-based segment max
__device__ __forceinline__ unsigned fmap(float x){
  unsigned b = __float_as_uint(x);
  return (b & 0x80000000u) ? ~b : (b | 0x80000000u);
}
__device__ __forceinline__ float funmap(unsigned k){
  return (k & 0x80000000u) ? __uint_as_float(k & 0x7FFFFFFFu) : __uint_as_float(~k);
}

// round-to-nearest-even bf16
__device__ __forceinline__ ushort bf16_rne(float a){
  unsigned u = __float_as_uint(a);
  return (ushort)((u + 0x7FFFu + ((u >> 16) & 1u)) >> 16);
}
__device__ __forceinline__ float b2f(ushort h){
  return __uint_as_float(((unsigned)h) << 16);
}

// async global->LDS, 16 B per lane; LDS dest = wave-uniform base + lane*16
__device__ __forceinline__ void lds_dma16(const void* g, void* l){
  __builtin_amdgcn_global_load_lds(
      (const __attribute__((address_space(1))) unsigned int*)(void*)g,
      (__attribute__((address_space(3))) unsigned int*)(void*)l, 16, 0, 0);
}

// ---------- one-time fp32 -> bf16 plane ----------
__global__ void to_bf16(const float* __restrict__ in, ushort* __restrict__ o, int n){
  int i = (blockIdx.x * blockDim.x + threadIdx.x) * 4;
  if(i >= n) return;
  float4 v = *(const float4*)(in + i);
  ushort4 r = make_ushort4(bf16_rne(v.x), bf16_rne(v.y), bf16_rne(v.z), bf16_rne(v.w));
  *(ushort4*)(o + i) = r;
}

// ---------- CSR build ----------
__global__ void deg_kernel(const int* __restrict__ dst, int* __restrict__ deg, int E){
  int e = blockIdx.x * blockDim.x + threadIdx.x;
  if(e < E) atomicAdd(&deg[dst[e]], 1);
}

__global__ void scan_block(const int* __restrict__ deg, int* __restrict__ incl,
                           int* __restrict__ bsum, int N){
  __shared__ int sm[1024];
  int t = threadIdx.x;
  int i = blockIdx.x * 1024 + t;
  int v = (i < N) ? deg[i] : 0;
  sm[t] = v;
  __syncthreads();
  for(int off = 1; off < 1024; off <<= 1){
    int a = (t >= off) ? sm[t - off] : 0;
    __syncthreads();
    sm[t] += a;
    __syncthreads();
  }
  if(i < N) incl[i] = sm[t];
  if(t == 1023) bsum[blockIdx.x] = sm[t];
}

__global__ void scan_bsum(const int* __restrict__ bsum, int* __restrict__ boff, int nb){
  __shared__ int sm[64];
  int t = threadIdx.x;
  sm[t] = (t < nb) ? bsum[t] : 0;
  __syncthreads();
  for(int off = 1; off < 64; off <<= 1){
    int a = (t >= off) ? sm[t - off] : 0;
    __syncthreads();
    sm[t] += a;
    __syncthreads();
  }
  if(t < nb) boff[t] = sm[t] - bsum[t];
}

__global__ void finalize_rows(const int* __restrict__ incl, const int* __restrict__ deg,
                              const int* __restrict__ boff, int* __restrict__ rows,
                              float* __restrict__ inv_deg, int N, int E){
  int i = blockIdx.x * blockDim.x + threadIdx.x;
  if(i < N){
    rows[i] = incl[i] - deg[i] + boff[i >> 10];
    inv_deg[i] = 1.0f / fmaxf((float)deg[i], 1.0f);
  }
  if(i == 0) rows[N] = E;
}

__global__ void csr_fill_kernel(const int* __restrict__ src, const int* __restrict__ dst,
                                const int* __restrict__ row_start, int* __restrict__ cursor,
                                int* __restrict__ csr, int E){
  int e = blockIdx.x * blockDim.x + threadIdx.x;
  if(e >= E) return;
  int d = dst[e];
  int p = atomicAdd(&cursor[d], 1);
  csr[row_start[d] + p] = src[e];
}

// ---------- aggregation: one 16-lane group per node ----------
// 16 lanes x 16 B = one whole 256-B bf16 row per load; 4 independent nodes/wave;
// x4 unroll -> up to 16 loads in flight per wave, 4 independent chains.
__global__ __launch_bounds__(256) void agg_csr_g16(
    const ushort* __restrict__ xb, const int* __restrict__ csr,
    const int* __restrict__ row_start, const float* __restrict__ inv_deg,
    ushort* __restrict__ mb, int N)
{
  int tid = threadIdx.x;
  int node = blockIdx.x * 16 + (tid >> 4);
  if(node >= N) return;
  int g15 = tid & 15;        // covers cols g15*8 .. g15*8+7
  int gbase = tid & 48;      // group's base lane within the wave
  int beg = row_start[node], end = row_start[node + 1];
  float a[8] = {0.f, 0.f, 0.f, 0.f, 0.f, 0.f, 0.f, 0.f};

  for(int base = beg; base < end; base += 16){
    int cnt = end - base; if(cnt > 16) cnt = 16;
    int s_l = (base + g15 < end) ? csr[base + g15] : 0;
    int j = 0;
    for(; j + 4 <= cnt; j += 4){
      int s0 = __shfl(s_l, gbase + j + 0, 64);
      int s1 = __shfl(s_l, gbase + j + 1, 64);
      int s2 = __shfl(s_l, gbase + j + 2, 64);
      int s3 = __shfl(s_l, gbase + j + 3, 64);
      short8 v0 = *(const short8*)(xb + (long long)s0 * C + g15 * 8);
      short8 v1 = *(const short8*)(xb + (long long)s1 * C + g15 * 8);
      short8 v2 = *(const short8*)(xb + (long long)s2 * C + g15 * 8);
      short8 v3 = *(const short8*)(xb + (long long)s3 * C + g15 * 8);
#pragma unroll
      for(int k = 0; k < 8; k++){
        a[k] += b2f((ushort)v0[k]);
        a[k] += b2f((ushort)v1[k]);
        a[k] += b2f((ushort)v2[k]);
        a[k] += b2f((ushort)v3[k]);
      }
    }
    for(; j < cnt; j++){
      int s = __shfl(s_l, gbase + j, 64);
      short8 v = *(const short8*)(xb + (long long)s * C + g15 * 8);
#pragma unroll
      for(int k = 0; k < 8; k++) a[k] += b2f((ushort)v[k]);
    }
  }
  float sc = inv_deg[node];
  short8 o;
#pragma unroll
  for(int k = 0; k < 8; k++) o[k] = (short)bf16_rne(a[k] * sc);
  *(short8*)(mb + (long long)node * C + g15 * 8) = o;
}

// ---------- weight pre-pack into MFMA B-fragment layout, bf16 hi/lo planes ----------
// B = [W_l ; W_r] (256 x 128).  frag index: (((kstep*4 + kg)*128 + n)*8 + j)
// where k = kstep*32 + kg*8 + j.  hi at [0 .. 32767], lo at [32768 ..].
__global__ void pack_kernel(const float* __restrict__ Wl, const float* __restrict__ Wr,
                            short* __restrict__ Bpk){
  int idx = blockIdx.x * blockDim.x + threadIdx.x;   // 0 .. 32767
  if(idx >= 2 * C * C) return;
  int k = idx >> 7, n = idx & 127;
  float w = (k < C) ? Wl[k * C + n] : Wr[(k - C) * C + n];
  ushort hi = bf16_rne(w);
  float r = w - b2f(hi);
  ushort lo = bf16_rne(r);
  int kstep = k >> 5, kg = (k >> 3) & 3, j = k & 7;
  int pos = ((kstep * 4 + kg) * C + n) * 8 + j;
  Bpk[pos] = (short)hi;
  Bpk[pos + 32768] = (short)lo;
}

// ---------- MFMA GEMM, m97-style async LDS staging ----------
// h = leakyrelu([mean | x] @ B + bias).  Tile 64 rows x 128 cols, 4 waves
// split by col strip (each 64x32); A tile (64 rows x 32 k bf16 = 4 KB) staged
// per k-step via global_load_lds (1 issue/thread, 16 B), XOR-swizzled so
// ds_read_b128 is <=2-way bank conflicted. B frags register-prefetched 1 ks
// ahead from packed global (L2-hot). 2 MFMA passes: A*Bhi + A*Blo.
__global__ __launch_bounds__(256, 2) void gemm_mfma5(
    const ushort* __restrict__ Amean, const ushort* __restrict__ Ax,
    const short* __restrict__ Bpk, const float* __restrict__ bias,
    ushort* __restrict__ Hout, int M,
    const int* __restrict__ batch, unsigned* __restrict__ pooled)
{
  __shared__ __align__(16) ushort As[64 * 32];   // 4 KB, single buffer
  int tid = threadIdx.x;
  int bm = blockIdx.x * 64;
  int lane = tid & 63;
  int wn = tid >> 6;         // wave = col strip (32 cols)
  int lg = lane >> 4;        // k-group (A/B frags), row-group (C/D)
  int lm = lane & 15;        // m (A) / n (B) / col (C/D)

  // staging map: thread t -> row t>>2, xor-swizzled 16-B slice
  int srow = tid >> 2;                         // 0..63
  int sslice = (tid & 3) ^ ((tid >> 3) & 3);
  int grow = bm + srow; if(grow >= M) grow = M - 1;   // clamp; extra rows discarded
  const long long goff = (long long)grow * C + sslice * 8;
  ushort* ldsbase = As + wn * 512;             // wave-uniform base (lane*16 B auto)

  f32x4 acc[4][2];
#pragma unroll
  for(int i = 0; i < 4; i++)
#pragma unroll
    for(int j = 0; j < 2; j++)
      acc[i][j] = (f32x4){0.f, 0.f, 0.f, 0.f};

  short8 bh[2][2], bl[2][2];
  auto loadB = [&](int ks, int buf){
#pragma unroll
    for(int j = 0; j < 2; j++){
      const short* bp = Bpk + (((ks * 4 + lg) * C) + wn * 32 + j * 16 + lm) * 8;
      bh[buf][j] = *(const short8*)bp;
      bl[buf][j] = *(const short8*)(bp + 32768);
    }
  };

  loadB(0, 0);
#pragma unroll
  for(int ks = 0; ks < 8; ks++){
    if(ks > 0) __syncthreads();                 // prior ks ds_reads done
    const ushort* Ap = (ks < 4) ? Amean : Ax;
    lds_dma16(Ap + goff + (ks & 3) * 32, ldsbase);
    if(ks < 7) loadB(ks + 1, (ks + 1) & 1);     // in flight across the drain
    __syncthreads();                            // drains DMA queue (vmcnt)

    short8 af[4];
#pragma unroll
    for(int i = 0; i < 4; i++){
      int r = i * 16 + lm;
      int slot = lg ^ ((r >> 1) & 3);
      af[i] = *(const short8*)(As + r * 32 + slot * 8);
    }
    int b = ks & 1;
#pragma unroll
    for(int i = 0; i < 4; i++)
#pragma unroll
      for(int j = 0; j < 2; j++){
        acc[i][j] = __builtin_amdgcn_mfma_f32_16x16x32_bf16(af[i], bh[b][j], acc[i][j], 0, 0, 0);
        acc[i][j] = __builtin_amdgcn_mfma_f32_16x16x32_bf16(af[i], bl[b][j], acc[i][j], 0, 0, 0);
      }
  }

  // ---- epilogue: C/D layout col=lane&15, row=(lane>>4)*4+reg ----
  if(pooled == nullptr){
#pragma unroll
    for(int j = 0; j < 2; j++){
      int col = wn * 32 + j * 16 + lm;
      float bv = bias[col];
#pragma unroll
      for(int i = 0; i < 4; i++){
#pragma unroll
        for(int reg = 0; reg < 4; reg++){
          int row = bm + i * 16 + lg * 4 + reg;
          if(row < M){
            float v = acc[i][j][reg] + bv;
            v = v > 0.f ? v : NEG_SLOPE * v;
            Hout[(long long)row * C + col] = bf16_rne(v);
          }
        }
      }
    }
  }else{
    // fused global-max-pool: reg-quad covers 4 consecutive rows
#pragma unroll
    for(int i = 0; i < 4; i++){
      int row0 = bm + i * 16 + lg * 4;
      if(row0 >= M) continue;
      bool whole = (row0 + 3 < M);
      int g0 = batch[row0];
      bool same = whole && (batch[row0 + 3] == g0);
#pragma unroll
      for(int j = 0; j < 2; j++){
        int col = wn * 32 + j * 16 + lm;
        float bv = bias[col];
        float v0 = acc[i][j][0] + bv; v0 = v0 > 0.f ? v0 : NEG_SLOPE * v0;
        float v1 = acc[i][j][1] + bv; v1 = v1 > 0.f ? v1 : NEG_SLOPE * v1;
        float v2 = acc[i][j][2] + bv; v2 = v2 > 0.f ? v2 : NEG_SLOPE * v2;
        float v3 = acc[i][j][3] + bv; v3 = v3 > 0.f ? v3 : NEG_SLOPE * v3;
        if(same){
          float m01 = fmaxf(v0, v1), m23 = fmaxf(v2, v3);
          atomicMax(&pooled[g0 * C + col], fmap(fmaxf(m01, m23)));
        }else{
          float vv[4] = {v0, v1, v2, v3};
#pragma unroll
          for(int reg = 0; reg < 4; reg++){
            int row = row0 + reg;
            if(row < M) atomicMax(&pooled[batch[row] * C + col], fmap(vv[reg]));
          }
        }
      }
    }
  }
}

__global__ void fc_kernel(const unsigned* __restrict__ pooled_u, const float* __restrict__ Wfc,
                          const float* __restrict__ bfc, float* __restrict__ out){
  int t = threadIdx.x;   // 0..127
  int g = t >> 1, o = t & 1;
  float s = bfc[o];
  for(int k = 0; k < C; k++)
    s += funmap(pooled_u[g * C + k]) * Wfc[k * 2 + o];
  out[g * 2 + o] = s;
}

extern "C" void kernel_launch(void* const* d_in, const int* in_sizes, int n_in,
                              void* d_out, int out_size, void* d_ws, size_t ws_size,
                              hipStream_t stream) {
  const float* x    = (const float*)d_in[0];
  const int*   ei   = (const int*)d_in[1];
  const int*   batch= (const int*)d_in[2];
  const float* W1l  = (const float*)d_in[3];
  const float* b1   = (const float*)d_in[4];
  const float* W1r  = (const float*)d_in[5];
  const float* W2l  = (const float*)d_in[6];
  const float* b2   = (const float*)d_in[7];
  const float* W2r  = (const float*)d_in[8];
  const float* W3l  = (const float*)d_in[9];
  const float* b3   = (const float*)d_in[10];
  const float* W3r  = (const float*)d_in[11];
  const float* Wfc  = (const float*)d_in[12];
  const float* bfc  = (const float*)d_in[13];
  float* out = (float*)d_out;

  const int N = in_sizes[0] / C;   // 50000
  const int E = in_sizes[1] / 2;   // 600000
  const int* srcv = ei;
  const int* dstv = ei + E;

  char* ws = (char*)d_ws;
  size_t off = 0;
  auto alloc = [&](size_t bytes) -> void* {
    void* p = ws + off;
    off += (bytes + 255) & ~(size_t)255;
    return p;
  };
  int*      deg    = (int*)alloc((size_t)N * 4);
  float*    inv_d  = (float*)alloc((size_t)N * 4);
  int*      incl   = (int*)alloc((size_t)N * 4);
  int*      bsum   = (int*)alloc((size_t)64 * 4);
  int*      boff   = (int*)alloc((size_t)64 * 4);
  int*      rows   = (int*)alloc((size_t)(N + 1) * 4);
  int*      cursor = (int*)alloc((size_t)N * 4);
  int*      csr    = (int*)alloc((size_t)E * 4);
  // bf16 activation planes
  ushort*   xb     = (ushort*)alloc((size_t)N * C * 2);
  ushort*   mb     = (ushort*)alloc((size_t)N * C * 2);
  ushort*   h1b    = (ushort*)alloc((size_t)N * C * 2);
  short*    B1     = (short*)alloc((size_t)2 * 2 * C * C * 2);
  short*    B2     = (short*)alloc((size_t)2 * 2 * C * C * 2);
  short*    B3     = (short*)alloc((size_t)2 * 2 * C * C * 2);
  unsigned* pooled = (unsigned*)alloc((size_t)NGRAPH * C * 4);

  hipMemsetAsync(deg, 0, (size_t)N * 4, stream);
  hipMemsetAsync(cursor, 0, (size_t)N * 4, stream);
  hipMemsetAsync(pooled, 0, (size_t)NGRAPH * C * 4, stream);

  const int nb = (N + 1023) / 1024;   // 49
  to_bf16<<<(N * C / 4 + 255) / 256, 256, 0, stream>>>(x, xb, N * C);
  deg_kernel<<<(E + 255) / 256, 256, 0, stream>>>(dstv, deg, E);
  scan_block<<<nb, 1024, 0, stream>>>(deg, incl, bsum, N);
  scan_bsum<<<1, 64, 0, stream>>>(bsum, boff, nb);
  finalize_rows<<<(N + 255) / 256, 256, 0, stream>>>(incl, deg, boff, rows, inv_d, N, E);
  csr_fill_kernel<<<(E + 255) / 256, 256, 0, stream>>>(srcv, dstv, rows, cursor, csr, E);

  pack_kernel<<<(2 * C * C + 255) / 256, 256, 0, stream>>>(W1l, W1r, B1);
  pack_kernel<<<(2 * C * C + 255) / 256, 256, 0, stream>>>(W2l, W2r, B2);
  pack_kernel<<<(2 * C * C + 255) / 256, 256, 0, stream>>>(W3l, W3r, B3);

  int gemmblocks = (N + 63) / 64;   // 782
  int aggblocks = (N + 15) / 16;    // 16 nodes (16-lane groups) per block

  // layer 1: x -> h1
  agg_csr_g16<<<aggblocks, 256, 0, stream>>>(xb, csr, rows, inv_d, mb, N);
  gemm_mfma5<<<gemmblocks, 256, 0, stream>>>(mb, xb, B1, b1, h1b, N, nullptr, nullptr);
  // layer 2: h1 -> h2 (stored into xb)
  agg_csr_g16<<<aggblocks, 256, 0, stream>>>(h1b, csr, rows, inv_d, mb, N);
  gemm_mfma5<<<gemmblocks, 256, 0, stream>>>(mb, h1b, B2, b2, xb, N, nullptr, nullptr);
  // layer 3: h2 -> pooled (fused global-max-pool epilogue)
  agg_csr_g16<<<aggblocks, 256, 0, stream>>>(xb, csr, rows, inv_d, mb, N);
  gemm_mfma5<<<gemmblocks, 256, 0, stream>>>(mb, xb, B3, b3, nullptr, N, batch, pooled);

  fc_kernel<<<1, 128, 0, stream>>>(pooled, Wfc, bfc, out);
}

// Round 9
// 287.181 us; speedup vs baseline: 1.5952x; 1.0879x over previous
//
#include <hip/hip_runtime.h>
#include <hip/hip_bf16.h>

#define NEG_SLOPE 0.01f
#define C 128
#define NGRAPH 64

typedef short short8 __attribute__((ext_vector_type(8)));
typedef float f32x4 __attribute__((ext_vector_type(4)));
typedef unsigned short ushort;

// monotone float <-> uint mapping for atomicMax-based segment max
__device__ __forceinline__ unsigned fmap(float x){
  unsigned b = __float_as_uint(x);
  return (b & 0x80000000u) ? ~b : (b | 0x80000000u);
}
__device__ __forceinline__ float funmap(unsigned k){
  return (k & 0x80000000u) ? __uint_as_float(k & 0x7FFFFFFFu) : __uint_as_float(~k);
}

// round-to-nearest-even bf16
__device__ __forceinline__ ushort bf16_rne(float a){
  unsigned u = __float_as_uint(a);
  return (ushort)((u + 0x7FFFu + ((u >> 16) & 1u)) >> 16);
}
__device__ __forceinline__ float b2f(ushort h){
  return __uint_as_float(((unsigned)h) << 16);
}

// async global->LDS, 16 B per lane; LDS dest = wave-uniform base + lane*16
__device__ __forceinline__ void lds_dma16(const void* g, void* l){
  __builtin_amdgcn_global_load_lds(
      (const __attribute__((address_space(1))) unsigned int*)(void*)g,
      (__attribute__((address_space(3))) unsigned int*)(void*)l, 16, 0, 0);
}

// ---------- prep: to_bf16 | deg | weight-pack, selected by blockIdx range ----------
// pack layout: B = [W_l ; W_r] (256 x 128). frag index (((kstep*4+kg)*128+n)*8+j),
// k = kstep*32 + kg*8 + j. hi plane at [0..32767], lo at [32768..].
__global__ void prep_kernel(const float* __restrict__ x, ushort* __restrict__ xb, int nx4,
                            const int* __restrict__ dst, int* __restrict__ deg, int E,
                            const float* __restrict__ W1l, const float* __restrict__ W1r,
                            const float* __restrict__ W2l, const float* __restrict__ W2r,
                            const float* __restrict__ W3l, const float* __restrict__ W3r,
                            short* __restrict__ B1, short* __restrict__ B2,
                            short* __restrict__ B3,
                            int nblk_x, int nblk_deg){
  int bid = blockIdx.x;
  if(bid < nblk_x){
    int i = (bid * 256 + threadIdx.x) * 4;
    if(i < nx4){
      float4 v = *(const float4*)(x + i);
      ushort4 r = make_ushort4(bf16_rne(v.x), bf16_rne(v.y), bf16_rne(v.z), bf16_rne(v.w));
      *(ushort4*)(xb + i) = r;
    }
    return;
  }
  bid -= nblk_x;
  if(bid < nblk_deg){
    int e = bid * 256 + threadIdx.x;
    if(e < E) atomicAdd(&deg[dst[e]], 1);
    return;
  }
  bid -= nblk_deg;
  int set = bid >> 7;              // 0..2  (128 blocks per weight set)
  int idx = (bid & 127) * 256 + threadIdx.x;   // 0..32767
  const float* Wl = (set == 0) ? W1l : (set == 1) ? W2l : W3l;
  const float* Wr = (set == 0) ? W1r : (set == 1) ? W2r : W3r;
  short* Bpk      = (set == 0) ? B1  : (set == 1) ? B2  : B3;
  int k = idx >> 7, n = idx & 127;
  float w = (k < C) ? Wl[k * C + n] : Wr[(k - C) * C + n];
  ushort hi = bf16_rne(w);
  float r = w - b2f(hi);
  ushort lo = bf16_rne(r);
  int kstep = k >> 5, kg = (k >> 3) & 3, j = k & 7;
  int pos = ((kstep * 4 + kg) * C + n) * 8 + j;
  Bpk[pos] = (short)hi;
  Bpk[pos + 32768] = (short)lo;
}

// ---------- CSR build ----------
__global__ void scan_block(const int* __restrict__ deg, int* __restrict__ incl,
                           int* __restrict__ bsum, int N){
  __shared__ int sm[1024];
  int t = threadIdx.x;
  int i = blockIdx.x * 1024 + t;
  int v = (i < N) ? deg[i] : 0;
  sm[t] = v;
  __syncthreads();
  for(int off = 1; off < 1024; off <<= 1){
    int a = (t >= off) ? sm[t - off] : 0;
    __syncthreads();
    sm[t] += a;
    __syncthreads();
  }
  if(i < N) incl[i] = sm[t];
  if(t == 1023) bsum[blockIdx.x] = sm[t];
}

__global__ void scan_bsum(const int* __restrict__ bsum, int* __restrict__ boff, int nb){
  __shared__ int sm[64];
  int t = threadIdx.x;
  sm[t] = (t < nb) ? bsum[t] : 0;
  __syncthreads();
  for(int off = 1; off < 64; off <<= 1){
    int a = (t >= off) ? sm[t - off] : 0;
    __syncthreads();
    sm[t] += a;
    __syncthreads();
  }
  if(t < nb) boff[t] = sm[t] - bsum[t];
}

__global__ void finalize_rows(const int* __restrict__ incl, const int* __restrict__ deg,
                              const int* __restrict__ boff, int* __restrict__ rows,
                              float* __restrict__ inv_deg, int N, int E){
  int i = blockIdx.x * blockDim.x + threadIdx.x;
  if(i < N){
    rows[i] = incl[i] - deg[i] + boff[i >> 10];
    inv_deg[i] = 1.0f / fmaxf((float)deg[i], 1.0f);
  }
  if(i == 0) rows[N] = E;
}

__global__ void csr_fill_kernel(const int* __restrict__ src, const int* __restrict__ dst,
                                const int* __restrict__ row_start, int* __restrict__ cursor,
                                int* __restrict__ csr, int E){
  int e = blockIdx.x * blockDim.x + threadIdx.x;
  if(e >= E) return;
  int d = dst[e];
  int p = atomicAdd(&cursor[d], 1);
  csr[row_start[d] + p] = src[e];
}

// ---------- fused layer: gather-mean (LDS tile) + MFMA GEMM ----------
// Block = 64 rows x 128 cols, 4 waves (col strips of 32).
// Phase 1: 16-lane group per node (16 groups x 4 nodes), mean -> Ms (bf16, +8 pad).
// Phase 2: ks 0..3 A-frags from Ms; ks 4..7 stage x tile via global_load_lds
// (xor-swizzled slices) as in m97. B frags register-prefetched 1 ks ahead.
// 2 MFMA passes per frag: A*Bhi + A*Blo (weights ~fp32-exact).
// pooled != nullptr: fused global-max-pool epilogue, no store.
__global__ __launch_bounds__(256, 2) void layer_fused(
    const ushort* __restrict__ xin, const int* __restrict__ csr,
    const int* __restrict__ rowp, const float* __restrict__ inv_deg,
    const short* __restrict__ Bpk, const float* __restrict__ bias,
    ushort* __restrict__ Hout, int M,
    const int* __restrict__ batch, unsigned* __restrict__ pooled)
{
  __shared__ ushort Ms[64 * 136];                 // mean tile, pad 8 shorts/row
  __shared__ __align__(16) ushort Xs[64 * 32];    // x staging (4 KB)
  int tid = threadIdx.x;
  int bm = blockIdx.x * 64;
  int lane = tid & 63;
  int wn = tid >> 6;         // wave = col strip
  int lg = lane >> 4;        // k-group (A/B frags), row-group (C/D)
  int lm = lane & 15;        // m (A) / n (B) / col (C/D)

  // ---- phase 1: aggregate means for rows bm..bm+63 ----
  {
    int grp = tid >> 4, g15 = tid & 15, gbase = tid & 48;
    for(int nn = grp; nn < 64; nn += 16){
      int node = bm + nn;
      float a[8] = {0.f, 0.f, 0.f, 0.f, 0.f, 0.f, 0.f, 0.f};
      if(node < M){
        int beg = rowp[node], end = rowp[node + 1];
        for(int base = beg; base < end; base += 16){
          int cnt = end - base; if(cnt > 16) cnt = 16;
          int s_l = (base + g15 < end) ? csr[base + g15] : 0;
          int j = 0;
          for(; j + 4 <= cnt; j += 4){
            int s0 = __shfl(s_l, gbase + j + 0, 64);
            int s1 = __shfl(s_l, gbase + j + 1, 64);
            int s2 = __shfl(s_l, gbase + j + 2, 64);
            int s3 = __shfl(s_l, gbase + j + 3, 64);
            short8 v0 = *(const short8*)(xin + (long long)s0 * C + g15 * 8);
            short8 v1 = *(const short8*)(xin + (long long)s1 * C + g15 * 8);
            short8 v2 = *(const short8*)(xin + (long long)s2 * C + g15 * 8);
            short8 v3 = *(const short8*)(xin + (long long)s3 * C + g15 * 8);
#pragma unroll
            for(int k = 0; k < 8; k++){
              a[k] += b2f((ushort)v0[k]); a[k] += b2f((ushort)v1[k]);
              a[k] += b2f((ushort)v2[k]); a[k] += b2f((ushort)v3[k]);
            }
          }
          for(; j < cnt; j++){
            int s = __shfl(s_l, gbase + j, 64);
            short8 v = *(const short8*)(xin + (long long)s * C + g15 * 8);
#pragma unroll
            for(int k = 0; k < 8; k++) a[k] += b2f((ushort)v[k]);
          }
        }
        float sc = inv_deg[node];
#pragma unroll
        for(int k = 0; k < 8; k++) a[k] *= sc;
      }
      short8 o;
#pragma unroll
      for(int k = 0; k < 8; k++) o[k] = (short)bf16_rne(a[k]);
      *(short8*)(Ms + nn * 136 + g15 * 8) = o;
    }
  }

  // ---- phase 2 setup ----
  int srow = tid >> 2;                          // 0..63
  int sslice = (tid & 3) ^ ((tid >> 3) & 3);    // xor-swizzled 16-B slice
  int grow = bm + srow; if(grow >= M) grow = M - 1;
  const long long goff = (long long)grow * C + sslice * 8;
  ushort* ldsbase = Xs + wn * 512;              // wave-uniform base

  f32x4 acc[4][2];
#pragma unroll
  for(int i = 0; i < 4; i++)
#pragma unroll
    for(int j = 0; j < 2; j++)
      acc[i][j] = (f32x4){0.f, 0.f, 0.f, 0.f};

  short8 bh[2][2], bl[2][2];
  auto loadB = [&](int ks, int buf){
#pragma unroll
    for(int j = 0; j < 2; j++){
      const short* bp = Bpk + (((ks * 4 + lg) * C) + wn * 32 + j * 16 + lm) * 8;
      bh[buf][j] = *(const short8*)bp;
      bl[buf][j] = *(const short8*)(bp + 32768);
    }
  };
  loadB(0, 0);
  __syncthreads();                              // Ms ready

#pragma unroll
  for(int ks = 0; ks < 8; ks++){
    if(ks >= 4){
      if(ks > 4) __syncthreads();               // prior Xs reads done
      lds_dma16(xin + goff + (ks - 4) * 32, ldsbase);
    }
    if(ks < 7) loadB(ks + 1, (ks + 1) & 1);
    if(ks >= 4) __syncthreads();                // drain DMA (vmcnt)

    short8 af[4];
    if(ks < 4){
#pragma unroll
      for(int i = 0; i < 4; i++)
        af[i] = *(const short8*)(Ms + (i * 16 + lm) * 136 + ks * 32 + lg * 8);
    }else{
#pragma unroll
      for(int i = 0; i < 4; i++){
        int r = i * 16 + lm;
        int slot = lg ^ ((r >> 1) & 3);
        af[i] = *(const short8*)(Xs + r * 32 + slot * 8);
      }
    }
    int b = ks & 1;
#pragma unroll
    for(int i = 0; i < 4; i++)
#pragma unroll
      for(int j = 0; j < 2; j++){
        acc[i][j] = __builtin_amdgcn_mfma_f32_16x16x32_bf16(af[i], bh[b][j], acc[i][j], 0, 0, 0);
        acc[i][j] = __builtin_amdgcn_mfma_f32_16x16x32_bf16(af[i], bl[b][j], acc[i][j], 0, 0, 0);
      }
  }

  // ---- epilogue: C/D layout col=lane&15, row=(lane>>4)*4+reg ----
  if(pooled == nullptr){
#pragma unroll
    for(int j = 0; j < 2; j++){
      int col = wn * 32 + j * 16 + lm;
      float bv = bias[col];
#pragma unroll
      for(int i = 0; i < 4; i++){
#pragma unroll
        for(int reg = 0; reg < 4; reg++){
          int row = bm + i * 16 + lg * 4 + reg;
          if(row < M){
            float v = acc[i][j][reg] + bv;
            v = v > 0.f ? v : NEG_SLOPE * v;
            Hout[(long long)row * C + col] = bf16_rne(v);
          }
        }
      }
    }
  }else{
    // fused global-max-pool: reg-quad covers 4 consecutive rows
#pragma unroll
    for(int i = 0; i < 4; i++){
      int row0 = bm + i * 16 + lg * 4;
      if(row0 >= M) continue;
      bool whole = (row0 + 3 < M);
      int g0 = batch[row0];
      bool same = whole && (batch[row0 + 3] == g0);
#pragma unroll
      for(int j = 0; j < 2; j++){
        int col = wn * 32 + j * 16 + lm;
        float bv = bias[col];
        float v0 = acc[i][j][0] + bv; v0 = v0 > 0.f ? v0 : NEG_SLOPE * v0;
        float v1 = acc[i][j][1] + bv; v1 = v1 > 0.f ? v1 : NEG_SLOPE * v1;
        float v2 = acc[i][j][2] + bv; v2 = v2 > 0.f ? v2 : NEG_SLOPE * v2;
        float v3 = acc[i][j][3] + bv; v3 = v3 > 0.f ? v3 : NEG_SLOPE * v3;
        if(same){
          float m01 = fmaxf(v0, v1), m23 = fmaxf(v2, v3);
          atomicMax(&pooled[g0 * C + col], fmap(fmaxf(m01, m23)));
        }else{
          float vv[4] = {v0, v1, v2, v3};
#pragma unroll
          for(int reg = 0; reg < 4; reg++){
            int row = row0 + reg;
            if(row < M) atomicMax(&pooled[batch[row] * C + col], fmap(vv[reg]));
          }
        }
      }
    }
  }
}

__global__ void fc_kernel(const unsigned* __restrict__ pooled_u, const float* __restrict__ Wfc,
                          const float* __restrict__ bfc, float* __restrict__ out){
  int t = threadIdx.x;   // 0..127
  int g = t >> 1, o = t & 1;
  float s = bfc[o];
  for(int k = 0; k < C; k++)
    s += funmap(pooled_u[g * C + k]) * Wfc[k * 2 + o];
  out[g * 2 + o] = s;
}

extern "C" void kernel_launch(void* const* d_in, const int* in_sizes, int n_in,
                              void* d_out, int out_size, void* d_ws, size_t ws_size,
                              hipStream_t stream) {
  const float* x    = (const float*)d_in[0];
  const int*   ei   = (const int*)d_in[1];
  const int*   batch= (const int*)d_in[2];
  const float* W1l  = (const float*)d_in[3];
  const float* b1   = (const float*)d_in[4];
  const float* W1r  = (const float*)d_in[5];
  const float* W2l  = (const float*)d_in[6];
  const float* b2   = (const float*)d_in[7];
  const float* W2r  = (const float*)d_in[8];
  const float* W3l  = (const float*)d_in[9];
  const float* b3   = (const float*)d_in[10];
  const float* W3r  = (const float*)d_in[11];
  const float* Wfc  = (const float*)d_in[12];
  const float* bfc  = (const float*)d_in[13];
  float* out = (float*)d_out;

  const int N = in_sizes[0] / C;   // 50000
  const int E = in_sizes[1] / 2;   // 600000
  const int* srcv = ei;
  const int* dstv = ei + E;

  char* ws = (char*)d_ws;
  size_t off = 0;
  auto alloc = [&](size_t bytes) -> void* {
    void* p = ws + off;
    off += (bytes + 255) & ~(size_t)255;
    return p;
  };
  // first three contiguous -> single memset
  int*      deg    = (int*)alloc((size_t)N * 4);
  int*      cursor = (int*)alloc((size_t)N * 4);
  unsigned* pooled = (unsigned*)alloc((size_t)NGRAPH * C * 4);
  size_t    zbytes = off;
  float*    inv_d  = (float*)alloc((size_t)N * 4);
  int*      incl   = (int*)alloc((size_t)N * 4);
  int*      bsum   = (int*)alloc((size_t)64 * 4);
  int*      boff   = (int*)alloc((size_t)64 * 4);
  int*      rows   = (int*)alloc((size_t)(N + 1) * 4);
  int*      csr    = (int*)alloc((size_t)E * 4);
  ushort*   xb     = (ushort*)alloc((size_t)N * C * 2);
  ushort*   h1b    = (ushort*)alloc((size_t)N * C * 2);
  short*    B1     = (short*)alloc((size_t)2 * 2 * C * C * 2);
  short*    B2     = (short*)alloc((size_t)2 * 2 * C * C * 2);
  short*    B3     = (short*)alloc((size_t)2 * 2 * C * C * 2);

  hipMemsetAsync(deg, 0, zbytes, stream);

  const int nbx  = (N * C / 4 + 255) / 256;   // to_bf16 blocks
  const int nbd  = (E + 255) / 256;           // deg blocks
  const int nbp  = 3 * 128;                   // pack blocks
  prep_kernel<<<nbx + nbd + nbp, 256, 0, stream>>>(
      x, xb, N * C, dstv, deg, E,
      W1l, W1r, W2l, W2r, W3l, W3r, B1, B2, B3, nbx, nbd);

  const int nb = (N + 1023) / 1024;   // 49
  scan_block<<<nb, 1024, 0, stream>>>(deg, incl, bsum, N);
  scan_bsum<<<1, 64, 0, stream>>>(bsum, boff, nb);
  finalize_rows<<<(N + 255) / 256, 256, 0, stream>>>(incl, deg, boff, rows, inv_d, N, E);
  csr_fill_kernel<<<(E + 255) / 256, 256, 0, stream>>>(srcv, dstv, rows, cursor, csr, E);

  int lblocks = (N + 63) / 64;   // 782

  // layer 1: x -> h1
  layer_fused<<<lblocks, 256, 0, stream>>>(xb, csr, rows, inv_d, B1, b1,
                                           h1b, N, nullptr, nullptr);
  // layer 2: h1 -> h2 (stored into xb)
  layer_fused<<<lblocks, 256, 0, stream>>>(h1b, csr, rows, inv_d, B2, b2,
                                           xb, N, nullptr, nullptr);
  // layer 3: h2 -> pooled (fused global-max-pool epilogue)
  layer_fused<<<lblocks, 256, 0, stream>>>(xb, csr, rows, inv_d, B3, b3,
                                           nullptr, N, batch, pooled);

  fc_kernel<<<1, 128, 0, stream>>>(pooled, Wfc, bfc, out);
}